// Round 9
// baseline (572.076 us; speedup 1.0000x reference)
//
#include <hip/hip_runtime.h>
#include <math.h>
#include <stdint.h>

#define TPB 256
#define NF 128          // feature width (all layers)
#define BN_EPS_C 1e-5f
#define BSH 9           // bucket shift: 512 nodes per bucket
#define PE_EPB 4096     // edges per block in count/partition

typedef __attribute__((ext_vector_type(8))) short bf16x8;   // 8 bf16 (4 VGPRs)
typedef __attribute__((ext_vector_type(4))) float f32x4;    // 4 fp32
typedef __attribute__((ext_vector_type(2))) float f32x2;    // 2 fp32 (v_pk_add_f32)

// ---------------------------------------------------------------------------
__device__ __forceinline__ void atomAddF(float* p, float v) {
    unsafeAtomicAdd(p, v);
}

// fp32 <-> bf16 (RNE), bit-level
__device__ __forceinline__ short f2bf(float f) {
    unsigned u = __float_as_uint(f);
    unsigned r = (u + 0x7FFFu + ((u >> 16) & 1u)) >> 16;
    return (short)r;
}
__device__ __forceinline__ float bf2f(short b) {
    return __uint_as_float(((unsigned)(unsigned short)b) << 16);
}
__device__ __forceinline__ float bflo(unsigned u) { return __uint_as_float(u << 16); }
__device__ __forceinline__ float bfhi(unsigned u) { return __uint_as_float(u & 0xffff0000u); }
__device__ __forceinline__ unsigned packbf(float lo, float hi) {
    return (unsigned)(unsigned short)f2bf(lo) | ((unsigned)(unsigned short)f2bf(hi) << 16);
}

// async 16B global -> LDS DMA (global_load_lds dwordx4)
__device__ __forceinline__ void async_copy16u(const unsigned short* g, unsigned short* l) {
    __builtin_amdgcn_global_load_lds(
        (const __attribute__((address_space(1))) unsigned int*)g,
        (__attribute__((address_space(3))) unsigned int*)l, 16, 0, 0);
}

// BN fold: (a,c) from column sums
__device__ __forceinline__ void bn_ac(float gs, float gq, float gamma, float beta,
                                      float invM, float* a, float* c) {
    float mean = gs * invM;
    float var  = fmaxf(gq * invM - mean * mean, 0.f);
    float s    = gamma / sqrtf(var + BN_EPS_C);
    *a = s;
    *c = beta - mean * s;
}

// ===========================================================================
// Bucketed CSR build (dst-grouped). Per-bucket srcs region is ~32KB
// (L2-resident) so scatter writes don't thrash HBM.
// ===========================================================================
__global__ __launch_bounds__(TPB) void bucket_count(
    const int* __restrict__ dst, int* __restrict__ bucket_cnt, int E, int nbuck)
{
    __shared__ int h[256];
    h[threadIdx.x] = 0;
    __syncthreads();
    int base = blockIdx.x * PE_EPB;
    int lim = min(base + PE_EPB, E);
    for (int i = base + threadIdx.x; i < lim; i += 256)
        atomicAdd(&h[dst[i] >> BSH], 1);
    __syncthreads();
    if (threadIdx.x < nbuck && h[threadIdx.x])
        atomicAdd(&bucket_cnt[threadIdx.x], h[threadIdx.x]);
}

__global__ __launch_bounds__(TPB) void bucket_scan(
    const int* __restrict__ bucket_cnt, int* __restrict__ boff,
    int* __restrict__ bucket_cur, int nbuck, int E)
{
    __shared__ int s[256];
    int t = threadIdx.x;
    int v = (t < nbuck) ? bucket_cnt[t] : 0;
    s[t] = v;
    __syncthreads();
    for (int off = 1; off < 256; off <<= 1) {
        int x = (t >= off) ? s[t - off] : 0;
        __syncthreads();
        s[t] += x;
        __syncthreads();
    }
    int excl = s[t] - v;
    if (t < nbuck) { boff[t] = excl; bucket_cur[t] = excl; }
    if (t == 0) boff[nbuck] = E;
}

// Pack edge as src | (dst&511)<<17  (M < 2^17; bucket id implied by region)
__global__ __launch_bounds__(TPB) void partition_edges(
    const int* __restrict__ src, const int* __restrict__ dst,
    int* __restrict__ bucket_cur, int* __restrict__ ppk, int E, int nbuck)
{
    __shared__ int cnt[256];
    __shared__ int gbase[256];
    int t = threadIdx.x;
    cnt[t] = 0;
    __syncthreads();
    int base = blockIdx.x * PE_EPB;
    int myb[16], myrank[16], myp[16];
#pragma unroll
    for (int j = 0; j < 16; ++j) {
        int i = base + j * 256 + t;
        if (i < E) {
            int d = dst[i];
            int b = d >> BSH;
            myb[j] = b;
            myp[j] = src[i] | ((d & 511) << 17);
            myrank[j] = atomicAdd(&cnt[b], 1);
        } else myb[j] = -1;
    }
    __syncthreads();
    if (t < nbuck && cnt[t]) gbase[t] = atomicAdd(&bucket_cur[t], cnt[t]);
    __syncthreads();
#pragma unroll
    for (int j = 0; j < 16; ++j)
        if (myb[j] >= 0)
            ppk[gbase[myb[j]] + myrank[j]] = myp[j];
}

__global__ __launch_bounds__(TPB) void bucket_build(
    const int* __restrict__ ppk, const int* __restrict__ boff,
    int* __restrict__ rowptr, int* __restrict__ srcs,
    float* __restrict__ degf, int M, int E)
{
    __shared__ int ldeg[512];
    __shared__ int lsum[256];
    int b = blockIdx.x;
    int t = threadIdx.x;
    int n0 = b << BSH;
    int nn = min(512, M - n0);
    int p0 = boff[b], p1 = boff[b + 1];
    ldeg[t] = 0; ldeg[t + 256] = 0;
    __syncthreads();
    for (int i = p0 + t; i < p1; i += 256)
        atomicAdd(&ldeg[ppk[i] >> 17], 1);
    __syncthreads();
    int a0 = ldeg[2 * t], a1 = ldeg[2 * t + 1];
    lsum[t] = a0 + a1;
    __syncthreads();
    for (int off = 1; off < 256; off <<= 1) {
        int x = (t >= off) ? lsum[t - off] : 0;
        __syncthreads();
        lsum[t] += x;
        __syncthreads();
    }
    int excl = lsum[t] - (a0 + a1);
    ldeg[2 * t]     = p0 + excl;            // becomes scatter cursor
    ldeg[2 * t + 1] = p0 + excl + a0;
    if (2 * t < nn)     { rowptr[n0 + 2 * t]     = p0 + excl;      degf[n0 + 2 * t]     = (float)a0; }
    if (2 * t + 1 < nn) { rowptr[n0 + 2 * t + 1] = p0 + excl + a0; degf[n0 + 2 * t + 1] = (float)a1; }
    if (b == 0 && t == 0) rowptr[M] = E;
    __syncthreads();
    for (int i = p0 + t; i < p1; i += 256) {
        int v = ppk[i];
        int pos = atomicAdd(&ldeg[v >> 17], 1);
        srcs[pos] = v & 0x1FFFF;
    }
}

// ===========================================================================
// x -> bf16 convert (once)
// ===========================================================================
__global__ __launch_bounds__(TPB) void cvt_bf16(
    const float* __restrict__ x, unsigned short* __restrict__ xb, int n8)
{
    int i = blockIdx.x * TPB + threadIdx.x;
    if (i >= n8) return;
    const f32x4* p = (const f32x4*)(x + (size_t)i * 8);
    f32x4 v0 = p[0], v1 = p[1];
    uint4 o;
    o.x = packbf(v0.x, v0.y); o.y = packbf(v0.z, v0.w);
    o.z = packbf(v1.x, v1.y); o.w = packbf(v1.z, v1.w);
    *(uint4*)(xb + (size_t)i * 8) = o;
}

// ===========================================================================
// Gather aggregation v3 (bf16 rows, packed-fp32 accumulate):
// one wave per node; 16-lane group g covers feats [li*8,+8) of edge e+4?g..
// f32x2 accumulators -> v_pk_add_f32 (adds halved); 16-edge unroll (4 uint4
// in flight per lane); predicated per-group tail (no fmaf masking).
// Output split into bf16 hi/lo planes for the GEMM.
// ===========================================================================
__device__ __forceinline__ void accp(f32x2* a, uint4 r) {
    a[0] += (f32x2){bflo(r.x), bfhi(r.x)};
    a[1] += (f32x2){bflo(r.y), bfhi(r.y)};
    a[2] += (f32x2){bflo(r.z), bfhi(r.z)};
    a[3] += (f32x2){bflo(r.w), bfhi(r.w)};
}

__global__ __launch_bounds__(TPB) void gather_bf16(
    const unsigned short* __restrict__ hb, const int* __restrict__ rowptr,
    const int* __restrict__ srcs,
    unsigned short* __restrict__ agg_hi, unsigned short* __restrict__ agg_lo, int M)
{
    int wid = (blockIdx.x * TPB + threadIdx.x) >> 6;
    if (wid >= M) return;
    int lane = threadIdx.x & 63;
    int grp  = lane >> 4;
    int li   = lane & 15;
    int start = rowptr[wid], end = rowptr[wid + 1];
    const unsigned short* base = hb + li * 8;

    f32x2 A0[4], A1[4], A2[4], A3[4];
#pragma unroll
    for (int j = 0; j < 4; ++j) {
        A0[j] = (f32x2){0.f, 0.f}; A1[j] = A0[j]; A2[j] = A0[j]; A3[j] = A0[j];
    }

    int e = start;
    for (; e + 15 < end; e += 16) {
        int s0 = srcs[e + grp];
        int s1 = srcs[e + 4 + grp];
        int s2 = srcs[e + 8 + grp];
        int s3 = srcs[e + 12 + grp];
        uint4 r0 = *(const uint4*)(base + (size_t)s0 * NF);
        uint4 r1 = *(const uint4*)(base + (size_t)s1 * NF);
        uint4 r2 = *(const uint4*)(base + (size_t)s2 * NF);
        uint4 r3 = *(const uint4*)(base + (size_t)s3 * NF);
        accp(A0, r0); accp(A1, r1); accp(A2, r2); accp(A3, r3);
    }
    for (; e + 3 < end; e += 4) {
        int s = srcs[e + grp];
        uint4 r = *(const uint4*)(base + (size_t)s * NF);
        accp(A0, r);
    }
    int rem = end - e;
    if (grp < rem) {
        int s = srcs[e + grp];
        uint4 r = *(const uint4*)(base + (size_t)s * NF);
        accp(A1, r);
    }

#pragma unroll
    for (int j = 0; j < 4; ++j) A0[j] = (A0[j] + A1[j]) + (A2[j] + A3[j]);
    float v[8] = {A0[0].x, A0[0].y, A0[1].x, A0[1].y,
                  A0[2].x, A0[2].y, A0[3].x, A0[3].y};
#pragma unroll
    for (int j = 0; j < 8; ++j) v[j] += __shfl_xor(v[j], 16);
#pragma unroll
    for (int j = 0; j < 8; ++j) v[j] += __shfl_xor(v[j], 32);

    if (lane < 16) {
        float h[8], l[8];
#pragma unroll
        for (int j = 0; j < 8; ++j) {
            h[j] = bf2f(f2bf(v[j]));
            l[j] = v[j] - h[j];
        }
        uint4 oh, ol;
        oh.x = packbf(h[0], h[1]); oh.y = packbf(h[2], h[3]);
        oh.z = packbf(h[4], h[5]); oh.w = packbf(h[6], h[7]);
        ol.x = packbf(l[0], l[1]); ol.y = packbf(l[2], l[3]);
        ol.z = packbf(l[4], l[5]); ol.w = packbf(l[6], l[7]);
        *(uint4*)(agg_hi + (size_t)wid * NF + li * 8) = oh;
        *(uint4*)(agg_lo + (size_t)wid * NF + li * 8) = ol;
    }
}

// ===========================================================================
// W pack layout (per layer): 8 chunks of 16 KB, DMA-linear.
// chunk kc holds concat-k range [kc*32, kc*32+32) for all 128 n.
// Within chunk: n row = 128 B = 8 slots of 16 B; logical slot 0..3 = hi
// (k-group lg), 4..7 = lo; PHYSICAL slot = logical ^ (n&7)  (bank swizzle).
// ===========================================================================
__device__ __forceinline__ void wpack_store(
    unsigned short* __restrict__ wpk, int n, int k, float w)
{
    short h = f2bf(w);
    short l = f2bf(w - bf2f(h));
    int kc = k >> 5, grp = (k >> 3) & 3, el = k & 7;
    int base = kc * 8192 + n * 64;
    wpk[base + ((grp      ) ^ (n & 7)) * 8 + el] = (unsigned short)h;
    wpk[base + ((grp ^ 4) ^ (n & 7)) * 8 + el] = (unsigned short)l;
}

// Layer-1 W prep (no norm): transpose + concat + split + pack.
__global__ __launch_bounds__(256) void wsplit_kernel(
    const float* __restrict__ Wr, const float* __restrict__ Wo,
    unsigned short* __restrict__ wpk)
{
    int n = blockIdx.x;      // 0..127
    int k = threadIdx.x;     // 0..255
    float v = (k < NF) ? Wr[k * NF + n] : Wo[(k - NF) * NF + n];
    wpack_store(wpk, n, k, v);
}

// Fold previous-layer BN (computed inline from gsum/gsq) into this layer's
// weights; also bias2 = b + c@Wroot, dvec = c@Wr.
__global__ __launch_bounds__(256) void fold_kernel(
    const float* __restrict__ gsum, const float* __restrict__ gsq,
    const float* __restrict__ gamma, const float* __restrict__ beta,
    const float* __restrict__ Wr, const float* __restrict__ Wo,
    const float* __restrict__ b,
    unsigned short* __restrict__ wpk,
    float* __restrict__ bias2, float* __restrict__ dvec, int M)
{
    __shared__ float red[256];
    int n = blockIdx.x;
    int k = threadIdx.x;
    int kk = k & 127;
    float a, c;
    bn_ac(gsum[kk], gsq[kk], gamma[kk], beta[kk], 1.0f / (float)M, &a, &c);
    float w = (k < NF) ? Wr[k * NF + n] : Wo[kk * NF + n];
    float contrib = c * w;
    w *= a;
    wpack_store(wpk, n, k, w);
    red[k] = contrib;
    __syncthreads();
    for (int off = 64; off >= 1; off >>= 1) {
        if ((k & 127) < off) red[k] += red[k + off];
        __syncthreads();
    }
    if (k == 0)   dvec[n]  = red[0];
    if (k == 128) bias2[n] = b[n] + red[128];
}

// ===========================================================================
// MFMA dual GEMM v5 — W LDS-staged (shared x4 waves), A direct + reg prefetch.
// ===========================================================================
template<bool RELU, bool NORM>
__global__ __launch_bounds__(TPB) void gemm_mfma(
    const unsigned short* __restrict__ Ahi, const unsigned short* __restrict__ Alo,
    const unsigned short* Ax,                                  // may alias C
    const unsigned short* __restrict__ wpk,
    const float* __restrict__ bias, const float* __restrict__ dvec,
    const float* __restrict__ degf, unsigned short* C,
    float* __restrict__ gsum, float* __restrict__ gsq, int M)
{
    __shared__ unsigned short sW[8192];    // 16 KB W chunk; reused for stats

    const int tid  = threadIdx.x;
    const int wid  = tid >> 6;
    const int lane = tid & 63;
    const int lg   = lane >> 4;        // quad 0..3
    const int ln   = lane & 15;
    const int rowbase = blockIdx.x * 128 + wid * 32;

    f32x4 acc[2][8];
#pragma unroll
    for (int i = 0; i < 2; ++i)
#pragma unroll
        for (int j = 0; j < 8; ++j) acc[i][j] = (f32x4){0.f, 0.f, 0.f, 0.f};

    size_t aoff[2];
#pragma unroll
    for (int mt = 0; mt < 2; ++mt)
        aoff[mt] = (size_t)min(rowbase + mt * 16 + ln, M - 1) * NF + lg * 8;

    // DMA chunk 0 + preload agg kc=0 A frags
    {
#pragma unroll
        for (int it = 0; it < 4; ++it) {
            int seg = it * 256 + tid;
            async_copy16u(wpk + seg * 8, sW + seg * 8);
        }
    }
    bf16x8 aH[2], aL[2], nH[2], nL[2];
#pragma unroll
    for (int mt = 0; mt < 2; ++mt) {
        aH[mt] = *(const bf16x8*)(Ahi + aoff[mt]);
        aL[mt] = *(const bf16x8*)(Alo + aoff[mt]);
    }

#pragma unroll
    for (int kc = 0; kc < 8; ++kc) {
        __syncthreads();               // chunk kc resident in sW

        // ---- prefetch next chunk's A fragments into registers
        if (kc < 3) {
#pragma unroll
            for (int mt = 0; mt < 2; ++mt) {
                nH[mt] = *(const bf16x8*)(Ahi + aoff[mt] + (kc + 1) * 32);
                nL[mt] = *(const bf16x8*)(Alo + aoff[mt] + (kc + 1) * 32);
            }
        } else if (kc < 7) {           // next is root chunk (kc+1-4)*32
#pragma unroll
            for (int mt = 0; mt < 2; ++mt)
                nH[mt] = *(const bf16x8*)(Ax + aoff[mt] + (kc - 3) * 32);
        }

        // ---- compute on chunk kc (W from LDS)
#pragma unroll
        for (int nt = 0; nt < 8; ++nt) {
            int n = nt * 16 + ln;
            int boff = n * 64 + ((lg ^ (n & 7)) << 3);
            bf16x8 bhi = *(const bf16x8*)(sW + boff);
            bf16x8 blo = *(const bf16x8*)(sW + (boff ^ 32));
            if (kc < 4) {
#pragma unroll
                for (int mt = 0; mt < 2; ++mt) {
                    acc[mt][nt] = __builtin_amdgcn_mfma_f32_16x16x32_bf16(aH[mt], bhi, acc[mt][nt], 0, 0, 0);
                    acc[mt][nt] = __builtin_amdgcn_mfma_f32_16x16x32_bf16(aL[mt], bhi, acc[mt][nt], 0, 0, 0);
                    acc[mt][nt] = __builtin_amdgcn_mfma_f32_16x16x32_bf16(aH[mt], blo, acc[mt][nt], 0, 0, 0);
                }
            } else {
#pragma unroll
                for (int mt = 0; mt < 2; ++mt) {
                    acc[mt][nt] = __builtin_amdgcn_mfma_f32_16x16x32_bf16(aH[mt], bhi, acc[mt][nt], 0, 0, 0);
                    acc[mt][nt] = __builtin_amdgcn_mfma_f32_16x16x32_bf16(aH[mt], blo, acc[mt][nt], 0, 0, 0);
                }
            }
        }

        __syncthreads();               // all waves done reading chunk kc
        if (kc < 7) {
            const unsigned short* src = wpk + (kc + 1) * 8192;
#pragma unroll
            for (int it = 0; it < 4; ++it) {
                int seg = it * 256 + tid;
                async_copy16u(src + seg * 8, sW + seg * 8);
            }
        }
#pragma unroll
        for (int mt = 0; mt < 2; ++mt) { aH[mt] = nH[mt]; aL[mt] = nL[mt]; }
    }

    // ---- epilogue: bias (+deg*dvec) (+ReLU), bf16 store, fused BN stats ----
    float B_[8], D_[8];
#pragma unroll
    for (int nt = 0; nt < 8; ++nt) {
        B_[nt] = bias[nt * 16 + ln];
        D_[nt] = NORM ? dvec[nt * 16 + ln] : 0.f;
    }
    float s8[8], q8[8];
#pragma unroll
    for (int nt = 0; nt < 8; ++nt) { s8[nt] = 0.f; q8[nt] = 0.f; }

#pragma unroll
    for (int mt = 0; mt < 2; ++mt) {
#pragma unroll
        for (int r = 0; r < 4; ++r) {
            int row = rowbase + mt * 16 + lg * 4 + r;
            if (row < M) {
                float dg = NORM ? degf[row] : 0.f;
#pragma unroll
                for (int nt = 0; nt < 8; ++nt) {
                    float v = acc[mt][nt][r] + B_[nt];
                    if (NORM) v += dg * D_[nt];
                    if (RELU) v = fmaxf(v, 0.f);
                    C[(size_t)row * NF + nt * 16 + ln] = (unsigned short)f2bf(v);
                    s8[nt] += v;
                    q8[nt] += v * v;
                }
            }
        }
    }

    __syncthreads();                   // done with sW as W buffer
    float* ssum = (float*)sW;          // [16][128]
    float* ssq  = ssum + 2048;
    const int rg = wid * 4 + lg;
#pragma unroll
    for (int nt = 0; nt < 8; ++nt) {
        ssum[rg * NF + nt * 16 + ln] = s8[nt];
        ssq [rg * NF + nt * 16 + ln] = q8[nt];
    }
    __syncthreads();
    if (tid < NF) {
        float s = 0.f, q = 0.f;
#pragma unroll
        for (int g = 0; g < 16; ++g) { s += ssum[g * NF + tid]; q += ssq[g * NF + tid]; }
        atomAddF(&gsum[tid], s);
        atomAddF(&gsq[tid], q);
    }
}

// ---------------------------------------------------------------------------
// Pooling (bf16 input): batch is SORTED -> run-length accumulate.
// ---------------------------------------------------------------------------
__global__ __launch_bounds__(TPB) void pool_kernel(
    const unsigned short* __restrict__ h, const int* __restrict__ batch,
    float* __restrict__ pooled, float* __restrict__ counts, int M)
{
    int base = blockIdx.x * 128;
    int col  = threadIdx.x & 127;
    int half = threadIdx.x >> 7;
    int end  = min(base + 128, M);
    float acc = 0.f; int cnt = 0; int gcur = -1;
    for (int n = base + half; n < end; n += 2) {
        int g = batch[n];
        if (g != gcur) {
            if (gcur >= 0) {
                atomAddF(&pooled[(size_t)gcur * NF + col], acc);
                if (col == 0) atomAddF(&counts[gcur], (float)cnt);
            }
            acc = 0.f; cnt = 0; gcur = g;
        }
        acc += bf2f((short)h[(size_t)n * NF + col]);
        cnt += 1;
    }
    if (gcur >= 0) {
        atomAddF(&pooled[(size_t)gcur * NF + col], acc);
        if (col == 0) atomAddF(&counts[gcur], (float)cnt);
    }
}

// Final: BN3 (computed inline) on pooled means, then @ Wlin + blin
__global__ __launch_bounds__(TPB) void final_kernel(
    const float* __restrict__ pooled, const float* __restrict__ counts,
    const float* __restrict__ gsum3, const float* __restrict__ gsq3,
    const float* __restrict__ g3, const float* __restrict__ be3,
    const float* __restrict__ Wlin, const float* __restrict__ blin,
    float* __restrict__ out, int G, int M)
{
    __shared__ float sa[128], sc[128];
    int t = threadIdx.x;
    if (t < 128) {
        float a, c;
        bn_ac(gsum3[t], gsq3[t], g3[t], be3[t], 1.0f / (float)M, &a, &c);
        sa[t] = a; sc[t] = c;
    }
    __syncthreads();
    int g = t;
    if (g >= G) return;
    float cntRaw = counts[g];
    float inv = 1.0f / fmaxf(cntRaw, 1.0f);
    float nonEmpty = cntRaw > 0.5f ? 1.0f : 0.0f;
    float acc0 = 0.f, acc1 = 0.f;
    for (int k = 0; k < NF; ++k) {
        float v = (sa[k] * pooled[(size_t)g * NF + k] * inv + sc[k]) * nonEmpty;
        acc0 += v * Wlin[k * 2 + 0];
        acc1 += v * Wlin[k * 2 + 1];
    }
    out[g * 2 + 0] = acc0 + blin[0];
    out[g * 2 + 1] = acc1 + blin[1];
}

// ---------------------------------------------------------------------------
extern "C" void kernel_launch(void* const* d_in, const int* in_sizes, int n_in,
                              void* d_out, int out_size, void* d_ws, size_t ws_size,
                              hipStream_t stream)
{
    const float* x     = (const float*)d_in[0];
    const int*   eidx  = (const int*)d_in[1];
    const int*   batch = (const int*)d_in[2];
    const float* W1r = (const float*)d_in[3],  *b1 = (const float*)d_in[4];
    const float* W1o = (const float*)d_in[5],  *g1 = (const float*)d_in[6],  *be1 = (const float*)d_in[7];
    const float* W2r = (const float*)d_in[8],  *b2 = (const float*)d_in[9];
    const float* W2o = (const float*)d_in[10], *g2 = (const float*)d_in[11], *be2 = (const float*)d_in[12];
    const float* W3r = (const float*)d_in[13], *b3 = (const float*)d_in[14];
    const float* W3o = (const float*)d_in[15], *g3 = (const float*)d_in[16], *be3 = (const float*)d_in[17];
    const float* Wlin = (const float*)d_in[18], *blin = (const float*)d_in[19];
    float* out = (float*)d_out;

    const int M = in_sizes[0] / NF;        // 100000 nodes (< 2^17 for pack)
    const int E = in_sizes[1] / 2;         // 1.6M edges
    const int G = out_size / 2;            // 256 graphs
    const int* src = eidx;
    const int* dst = eidx + E;
    const int nbuck = (M + 511) >> BSH;

    const size_t NODEF = (size_t)M * NF;

    // ---- workspace layout (four bf16 node-feature planes) ----
    unsigned short* agg_hi = (unsigned short*)d_ws;       // NODEF bf16
    unsigned short* agg_lo = agg_hi + NODEF;              // NODEF bf16
    unsigned short* xb     = agg_lo + NODEF;              // NODEF bf16
    unsigned short* hb     = xb + NODEF;                  // NODEF bf16
    float* zf   = (float*)(hb + NODEF);            // zeroed float zone
    float* gsum1 = zf;        float* gsq1 = zf + 128;
    float* gsum2 = zf + 256;  float* gsq2 = zf + 384;
    float* gsum3 = zf + 512;  float* gsq3 = zf + 640;
    float* counts = zf + 768;                      // G
    float* pooled = counts + G;                    // G*NF
    int*   zi   = (int*)(pooled + (size_t)G * NF); // zeroed int zone (1024)
    int* bucket_cnt = zi;                          // 256
    int* bucket_cur = zi + 256;                    // 256
    int* boff       = zi + 512;                    // nbuck+1 (<=257)
    int* ziEnd      = zi + 1024;
    float* ac = (float*)ziEnd;                     // fold outs
    float* bias2_2 = ac;        float* dvec2 = ac + 128;
    float* bias2_3 = ac + 256;  float* dvec3 = ac + 384;
    int* rowptr = (int*)(ac + 512);                // M+1
    int* srcs   = rowptr + (M + 1);                // E
    float* degf = (float*)(srcs + E);              // M
    uintptr_t pp = ((uintptr_t)(degf + M) + 15) & ~(uintptr_t)15;
    int* ppk = (int*)pp;                           // E packed edges (CSR build)
    // packed-W buffers UNION with ppk (dead before wsplit/fold run)
    unsigned short* wpk1 = (unsigned short*)pp;    // 65536 each (128 KB)
    unsigned short* wpk2 = wpk1 + 65536;
    unsigned short* wpk3 = wpk2 + 65536;

    const int gridEP       = (E + PE_EPB - 1) / PE_EPB;
    const int gatherBlocks = (int)(((size_t)M * 64 + TPB - 1) / TPB);
    const int gemmBlocks   = (M + 127) / 128;
    const int poolBlocks   = (M + 127) / 128;
    const int cvtBlocks    = (int)((NODEF / 8 + TPB - 1) / TPB);

    // single memset: float zone + int zone
    size_t zbytes = (char*)ziEnd - (char*)zf;
    hipMemsetAsync(zf, 0, zbytes, stream);

    // ---- bucketed reverse-CSR build (dst-grouped), reused by all 3 layers
    bucket_count   <<<gridEP, TPB, 0, stream>>>(dst, bucket_cnt, E, nbuck);
    bucket_scan    <<<1, TPB, 0, stream>>>(bucket_cnt, boff, bucket_cur, nbuck, E);
    partition_edges<<<gridEP, TPB, 0, stream>>>(src, dst, bucket_cur, ppk, E, nbuck);
    bucket_build   <<<nbuck, TPB, 0, stream>>>(ppk, boff, rowptr, srcs, degf, M, E);

    // ---- x -> bf16
    cvt_bf16<<<cvtBlocks, TPB, 0, stream>>>(x, xb, (int)(NODEF / 8));

    // ---- layer 1 (no incoming norm)
    wsplit_kernel<<<128, 256, 0, stream>>>(W1r, W1o, wpk1);
    gather_bf16<<<gatherBlocks, TPB, 0, stream>>>(xb, rowptr, srcs, agg_hi, agg_lo, M);
    gemm_mfma<true, false><<<gemmBlocks, TPB, 0, stream>>>(
        agg_hi, agg_lo, xb, wpk1, b1, nullptr, nullptr, hb, gsum1, gsq1, M);

    // ---- layer 2 (BN1 computed in fold, folded into weights)
    fold_kernel<<<128, 256, 0, stream>>>(gsum1, gsq1, g1, be1, W2r, W2o, b2,
                                         wpk2, bias2_2, dvec2, M);
    gather_bf16<<<gatherBlocks, TPB, 0, stream>>>(hb, rowptr, srcs, agg_hi, agg_lo, M);
    gemm_mfma<true, true><<<gemmBlocks, TPB, 0, stream>>>(
        agg_hi, agg_lo, hb, wpk2, bias2_2, dvec2, degf, hb, gsum2, gsq2, M);

    // ---- layer 3 (no ReLU; BN2 computed in fold, folded into weights)
    fold_kernel<<<128, 256, 0, stream>>>(gsum2, gsq2, g2, be2, W3r, W3o, b3,
                                         wpk3, bias2_3, dvec3, M);
    gather_bf16<<<gatherBlocks, TPB, 0, stream>>>(hb, rowptr, srcs, agg_hi, agg_lo, M);
    gemm_mfma<false, true><<<gemmBlocks, TPB, 0, stream>>>(
        agg_hi, agg_lo, hb, wpk3, bias2_3, dvec3, degf, hb, gsum3, gsq3, M);

    // ---- pool + classify (BN3 computed inline in final)
    pool_kernel<<<poolBlocks, TPB, 0, stream>>>(hb, batch, pooled, counts, M);
    final_kernel<<<1, TPB, 0, stream>>>(pooled, counts, gsum3, gsq3, g3, be3,
                                        Wlin, blin, out, G, M);
}

// Round 10
// 550.265 us; speedup vs baseline: 1.0396x; 1.0396x over previous
//
#include <hip/hip_runtime.h>
#include <math.h>
#include <stdint.h>

#define TPB 256
#define NF 128          // feature width (all layers)
#define BN_EPS_C 1e-5f
#define BSH 9           // bucket shift: 512 nodes per bucket
#define PE_EPB 4096     // edges per block in count/partition

typedef __attribute__((ext_vector_type(8))) short bf16x8;   // 8 bf16 (4 VGPRs)
typedef __attribute__((ext_vector_type(4))) float f32x4;    // 4 fp32
typedef __attribute__((ext_vector_type(2))) float f32x2;    // 2 fp32 (v_pk_add_f32)

// ---------------------------------------------------------------------------
__device__ __forceinline__ void atomAddF(float* p, float v) {
    unsafeAtomicAdd(p, v);
}

// fp32 <-> bf16 (RNE), bit-level
__device__ __forceinline__ short f2bf(float f) {
    unsigned u = __float_as_uint(f);
    unsigned r = (u + 0x7FFFu + ((u >> 16) & 1u)) >> 16;
    return (short)r;
}
__device__ __forceinline__ float bf2f(short b) {
    return __uint_as_float(((unsigned)(unsigned short)b) << 16);
}
__device__ __forceinline__ float bflo(unsigned u) { return __uint_as_float(u << 16); }
__device__ __forceinline__ float bfhi(unsigned u) { return __uint_as_float(u & 0xffff0000u); }
__device__ __forceinline__ unsigned packbf(float lo, float hi) {
    return (unsigned)(unsigned short)f2bf(lo) | ((unsigned)(unsigned short)f2bf(hi) << 16);
}

// async 16B global -> LDS DMA (global_load_lds dwordx4)
__device__ __forceinline__ void async_copy16u(const unsigned short* g, unsigned short* l) {
    __builtin_amdgcn_global_load_lds(
        (const __attribute__((address_space(1))) unsigned int*)g,
        (__attribute__((address_space(3))) unsigned int*)l, 16, 0, 0);
}

// BN fold: (a,c) from column sums
__device__ __forceinline__ void bn_ac(float gs, float gq, float gamma, float beta,
                                      float invM, float* a, float* c) {
    float mean = gs * invM;
    float var  = fmaxf(gq * invM - mean * mean, 0.f);
    float s    = gamma / sqrtf(var + BN_EPS_C);
    *a = s;
    *c = beta - mean * s;
}

// ===========================================================================
// Bucketed CSR build (dst-grouped). Per-bucket srcs region is ~32KB
// (L2-resident) so scatter writes don't thrash HBM.
// ===========================================================================
__global__ __launch_bounds__(TPB) void bucket_count(
    const int* __restrict__ dst, int* __restrict__ bucket_cnt, int E, int nbuck)
{
    __shared__ int h[256];
    h[threadIdx.x] = 0;
    __syncthreads();
    int base = blockIdx.x * PE_EPB;
    int lim = min(base + PE_EPB, E);
    for (int i = base + threadIdx.x; i < lim; i += 256)
        atomicAdd(&h[dst[i] >> BSH], 1);
    __syncthreads();
    if (threadIdx.x < nbuck && h[threadIdx.x])
        atomicAdd(&bucket_cnt[threadIdx.x], h[threadIdx.x]);
}

__global__ __launch_bounds__(TPB) void bucket_scan(
    const int* __restrict__ bucket_cnt, int* __restrict__ boff,
    int* __restrict__ bucket_cur, int nbuck, int E)
{
    __shared__ int s[256];
    int t = threadIdx.x;
    int v = (t < nbuck) ? bucket_cnt[t] : 0;
    s[t] = v;
    __syncthreads();
    for (int off = 1; off < 256; off <<= 1) {
        int x = (t >= off) ? s[t - off] : 0;
        __syncthreads();
        s[t] += x;
        __syncthreads();
    }
    int excl = s[t] - v;
    if (t < nbuck) { boff[t] = excl; bucket_cur[t] = excl; }
    if (t == 0) boff[nbuck] = E;
}

// Pack edge as src | (dst&511)<<17  (M < 2^17; bucket id implied by region)
__global__ __launch_bounds__(TPB) void partition_edges(
    const int* __restrict__ src, const int* __restrict__ dst,
    int* __restrict__ bucket_cur, int* __restrict__ ppk, int E, int nbuck)
{
    __shared__ int cnt[256];
    __shared__ int gbase[256];
    int t = threadIdx.x;
    cnt[t] = 0;
    __syncthreads();
    int base = blockIdx.x * PE_EPB;
    int myb[16], myrank[16], myp[16];
#pragma unroll
    for (int j = 0; j < 16; ++j) {
        int i = base + j * 256 + t;
        if (i < E) {
            int d = dst[i];
            int b = d >> BSH;
            myb[j] = b;
            myp[j] = src[i] | ((d & 511) << 17);
            myrank[j] = atomicAdd(&cnt[b], 1);
        } else myb[j] = -1;
    }
    __syncthreads();
    if (t < nbuck && cnt[t]) gbase[t] = atomicAdd(&bucket_cur[t], cnt[t]);
    __syncthreads();
#pragma unroll
    for (int j = 0; j < 16; ++j)
        if (myb[j] >= 0)
            ppk[gbase[myb[j]] + myrank[j]] = myp[j];
}

__global__ __launch_bounds__(TPB) void bucket_build(
    const int* __restrict__ ppk, const int* __restrict__ boff,
    int* __restrict__ rowptr, int* __restrict__ srcs,
    float* __restrict__ degf, int M, int E)
{
    __shared__ int ldeg[512];
    __shared__ int lsum[256];
    int b = blockIdx.x;
    int t = threadIdx.x;
    int n0 = b << BSH;
    int nn = min(512, M - n0);
    int p0 = boff[b], p1 = boff[b + 1];
    ldeg[t] = 0; ldeg[t + 256] = 0;
    __syncthreads();
    for (int i = p0 + t; i < p1; i += 256)
        atomicAdd(&ldeg[ppk[i] >> 17], 1);
    __syncthreads();
    int a0 = ldeg[2 * t], a1 = ldeg[2 * t + 1];
    lsum[t] = a0 + a1;
    __syncthreads();
    for (int off = 1; off < 256; off <<= 1) {
        int x = (t >= off) ? lsum[t - off] : 0;
        __syncthreads();
        lsum[t] += x;
        __syncthreads();
    }
    int excl = lsum[t] - (a0 + a1);
    ldeg[2 * t]     = p0 + excl;            // becomes scatter cursor
    ldeg[2 * t + 1] = p0 + excl + a0;
    if (2 * t < nn)     { rowptr[n0 + 2 * t]     = p0 + excl;      degf[n0 + 2 * t]     = (float)a0; }
    if (2 * t + 1 < nn) { rowptr[n0 + 2 * t + 1] = p0 + excl + a0; degf[n0 + 2 * t + 1] = (float)a1; }
    if (b == 0 && t == 0) rowptr[M] = E;
    __syncthreads();
    for (int i = p0 + t; i < p1; i += 256) {
        int v = ppk[i];
        int pos = atomicAdd(&ldeg[v >> 17], 1);
        srcs[pos] = v & 0x1FFFF;
    }
}

// ===========================================================================
// x -> bf16 convert (once)
// ===========================================================================
__global__ __launch_bounds__(TPB) void cvt_bf16(
    const float* __restrict__ x, unsigned short* __restrict__ xb, int n8)
{
    int i = blockIdx.x * TPB + threadIdx.x;
    if (i >= n8) return;
    const f32x4* p = (const f32x4*)(x + (size_t)i * 8);
    f32x4 v0 = p[0], v1 = p[1];
    uint4 o;
    o.x = packbf(v0.x, v0.y); o.y = packbf(v0.z, v0.w);
    o.z = packbf(v1.x, v1.y); o.w = packbf(v1.z, v1.w);
    *(uint4*)(xb + (size_t)i * 8) = o;
}

// ===========================================================================
// Gather aggregation v4 (R8 shape + packed adds):
// one wave per node; 16-lane group g covers feats [li*8,+8) of edge e+grp.
// 8-edge flight (2 uint4 loads in flight per lane, small VGPR footprint ->
// high occupancy; R9's 16-edge unroll doubled VGPR and regressed).
// f32x2 accumulators -> v_pk_add_f32 halves add count at SAME register cost.
// Output split into bf16 hi/lo planes for the GEMM.
// ===========================================================================
__device__ __forceinline__ void accp(f32x2* a, uint4 r) {
    a[0] += (f32x2){bflo(r.x), bfhi(r.x)};
    a[1] += (f32x2){bflo(r.y), bfhi(r.y)};
    a[2] += (f32x2){bflo(r.z), bfhi(r.z)};
    a[3] += (f32x2){bflo(r.w), bfhi(r.w)};
}

__global__ __launch_bounds__(TPB) void gather_bf16(
    const unsigned short* __restrict__ hb, const int* __restrict__ rowptr,
    const int* __restrict__ srcs,
    unsigned short* __restrict__ agg_hi, unsigned short* __restrict__ agg_lo, int M)
{
    int wid = (blockIdx.x * TPB + threadIdx.x) >> 6;
    if (wid >= M) return;
    int lane = threadIdx.x & 63;
    int grp  = lane >> 4;
    int li   = lane & 15;
    int start = rowptr[wid], end = rowptr[wid + 1];
    const unsigned short* base = hb + li * 8;

    f32x2 A0[4], A1[4];
#pragma unroll
    for (int j = 0; j < 4; ++j) { A0[j] = (f32x2){0.f, 0.f}; A1[j] = A0[j]; }

    int e = start;
    for (; e + 7 < end; e += 8) {
        int s0 = srcs[e + grp];
        int s1 = srcs[e + 4 + grp];
        uint4 r0 = *(const uint4*)(base + (size_t)s0 * NF);
        uint4 r1 = *(const uint4*)(base + (size_t)s1 * NF);
        accp(A0, r0);
        accp(A1, r1);
    }
    if (e + 3 < end) {                 // at most one 4-edge step remains
        int s = srcs[e + grp];
        uint4 r = *(const uint4*)(base + (size_t)s * NF);
        accp(A0, r);
        e += 4;
    }
    int rem = end - e;                 // 0..3: predicated per-group tail
    if (grp < rem) {
        int s = srcs[e + grp];
        uint4 r = *(const uint4*)(base + (size_t)s * NF);
        accp(A1, r);
    }

#pragma unroll
    for (int j = 0; j < 4; ++j) A0[j] += A1[j];
    float v[8] = {A0[0].x, A0[0].y, A0[1].x, A0[1].y,
                  A0[2].x, A0[2].y, A0[3].x, A0[3].y};
#pragma unroll
    for (int j = 0; j < 8; ++j) v[j] += __shfl_xor(v[j], 16);
#pragma unroll
    for (int j = 0; j < 8; ++j) v[j] += __shfl_xor(v[j], 32);

    if (lane < 16) {
        float h[8], l[8];
#pragma unroll
        for (int j = 0; j < 8; ++j) {
            h[j] = bf2f(f2bf(v[j]));
            l[j] = v[j] - h[j];
        }
        uint4 oh, ol;
        oh.x = packbf(h[0], h[1]); oh.y = packbf(h[2], h[3]);
        oh.z = packbf(h[4], h[5]); oh.w = packbf(h[6], h[7]);
        ol.x = packbf(l[0], l[1]); ol.y = packbf(l[2], l[3]);
        ol.z = packbf(l[4], l[5]); ol.w = packbf(l[6], l[7]);
        *(uint4*)(agg_hi + (size_t)wid * NF + li * 8) = oh;
        *(uint4*)(agg_lo + (size_t)wid * NF + li * 8) = ol;
    }
}

// ===========================================================================
// W pack layout (per layer): 8 chunks of 16 KB, DMA-linear.
// chunk kc holds concat-k range [kc*32, kc*32+32) for all 128 n.
// Within chunk: n row = 128 B = 8 slots of 16 B; logical slot 0..3 = hi
// (k-group lg), 4..7 = lo; PHYSICAL slot = logical ^ (n&7)  (bank swizzle).
// ===========================================================================
__device__ __forceinline__ void wpack_store(
    unsigned short* __restrict__ wpk, int n, int k, float w)
{
    short h = f2bf(w);
    short l = f2bf(w - bf2f(h));
    int kc = k >> 5, grp = (k >> 3) & 3, el = k & 7;
    int base = kc * 8192 + n * 64;
    wpk[base + ((grp      ) ^ (n & 7)) * 8 + el] = (unsigned short)h;
    wpk[base + ((grp ^ 4) ^ (n & 7)) * 8 + el] = (unsigned short)l;
}

// Layer-1 W prep (no norm): transpose + concat + split + pack.
__global__ __launch_bounds__(256) void wsplit_kernel(
    const float* __restrict__ Wr, const float* __restrict__ Wo,
    unsigned short* __restrict__ wpk)
{
    int n = blockIdx.x;      // 0..127
    int k = threadIdx.x;     // 0..255
    float v = (k < NF) ? Wr[k * NF + n] : Wo[(k - NF) * NF + n];
    wpack_store(wpk, n, k, v);
}

// Fold previous-layer BN (computed inline from gsum/gsq) into this layer's
// weights; also bias2 = b + c@Wroot, dvec = c@Wr.
__global__ __launch_bounds__(256) void fold_kernel(
    const float* __restrict__ gsum, const float* __restrict__ gsq,
    const float* __restrict__ gamma, const float* __restrict__ beta,
    const float* __restrict__ Wr, const float* __restrict__ Wo,
    const float* __restrict__ b,
    unsigned short* __restrict__ wpk,
    float* __restrict__ bias2, float* __restrict__ dvec, int M)
{
    __shared__ float red[256];
    int n = blockIdx.x;
    int k = threadIdx.x;
    int kk = k & 127;
    float a, c;
    bn_ac(gsum[kk], gsq[kk], gamma[kk], beta[kk], 1.0f / (float)M, &a, &c);
    float w = (k < NF) ? Wr[k * NF + n] : Wo[kk * NF + n];
    float contrib = c * w;
    w *= a;
    wpack_store(wpk, n, k, w);
    red[k] = contrib;
    __syncthreads();
    for (int off = 64; off >= 1; off >>= 1) {
        if ((k & 127) < off) red[k] += red[k + off];
        __syncthreads();
    }
    if (k == 0)   dvec[n]  = red[0];
    if (k == 128) bias2[n] = b[n] + red[128];
}

// ===========================================================================
// MFMA dual GEMM v5 — W LDS-staged (shared x4 waves), A direct + reg prefetch.
// ===========================================================================
template<bool RELU, bool NORM>
__global__ __launch_bounds__(TPB) void gemm_mfma(
    const unsigned short* __restrict__ Ahi, const unsigned short* __restrict__ Alo,
    const unsigned short* Ax,                                  // may alias C
    const unsigned short* __restrict__ wpk,
    const float* __restrict__ bias, const float* __restrict__ dvec,
    const float* __restrict__ degf, unsigned short* C,
    float* __restrict__ gsum, float* __restrict__ gsq, int M)
{
    __shared__ unsigned short sW[8192];    // 16 KB W chunk; reused for stats

    const int tid  = threadIdx.x;
    const int wid  = tid >> 6;
    const int lane = tid & 63;
    const int lg   = lane >> 4;        // quad 0..3
    const int ln   = lane & 15;
    const int rowbase = blockIdx.x * 128 + wid * 32;

    f32x4 acc[2][8];
#pragma unroll
    for (int i = 0; i < 2; ++i)
#pragma unroll
        for (int j = 0; j < 8; ++j) acc[i][j] = (f32x4){0.f, 0.f, 0.f, 0.f};

    size_t aoff[2];
#pragma unroll
    for (int mt = 0; mt < 2; ++mt)
        aoff[mt] = (size_t)min(rowbase + mt * 16 + ln, M - 1) * NF + lg * 8;

    // DMA chunk 0 + preload agg kc=0 A frags
    {
#pragma unroll
        for (int it = 0; it < 4; ++it) {
            int seg = it * 256 + tid;
            async_copy16u(wpk + seg * 8, sW + seg * 8);
        }
    }
    bf16x8 aH[2], aL[2], nH[2], nL[2];
#pragma unroll
    for (int mt = 0; mt < 2; ++mt) {
        aH[mt] = *(const bf16x8*)(Ahi + aoff[mt]);
        aL[mt] = *(const bf16x8*)(Alo + aoff[mt]);
    }

#pragma unroll
    for (int kc = 0; kc < 8; ++kc) {
        __syncthreads();               // chunk kc resident in sW

        // ---- prefetch next chunk's A fragments into registers
        if (kc < 3) {
#pragma unroll
            for (int mt = 0; mt < 2; ++mt) {
                nH[mt] = *(const bf16x8*)(Ahi + aoff[mt] + (kc + 1) * 32);
                nL[mt] = *(const bf16x8*)(Alo + aoff[mt] + (kc + 1) * 32);
            }
        } else if (kc < 7) {           // next is root chunk (kc+1-4)*32
#pragma unroll
            for (int mt = 0; mt < 2; ++mt)
                nH[mt] = *(const bf16x8*)(Ax + aoff[mt] + (kc - 3) * 32);
        }

        // ---- compute on chunk kc (W from LDS)
#pragma unroll
        for (int nt = 0; nt < 8; ++nt) {
            int n = nt * 16 + ln;
            int boff = n * 64 + ((lg ^ (n & 7)) << 3);
            bf16x8 bhi = *(const bf16x8*)(sW + boff);
            bf16x8 blo = *(const bf16x8*)(sW + (boff ^ 32));
            if (kc < 4) {
#pragma unroll
                for (int mt = 0; mt < 2; ++mt) {
                    acc[mt][nt] = __builtin_amdgcn_mfma_f32_16x16x32_bf16(aH[mt], bhi, acc[mt][nt], 0, 0, 0);
                    acc[mt][nt] = __builtin_amdgcn_mfma_f32_16x16x32_bf16(aL[mt], bhi, acc[mt][nt], 0, 0, 0);
                    acc[mt][nt] = __builtin_amdgcn_mfma_f32_16x16x32_bf16(aH[mt], blo, acc[mt][nt], 0, 0, 0);
                }
            } else {
#pragma unroll
                for (int mt = 0; mt < 2; ++mt) {
                    acc[mt][nt] = __builtin_amdgcn_mfma_f32_16x16x32_bf16(aH[mt], bhi, acc[mt][nt], 0, 0, 0);
                    acc[mt][nt] = __builtin_amdgcn_mfma_f32_16x16x32_bf16(aH[mt], blo, acc[mt][nt], 0, 0, 0);
                }
            }
        }

        __syncthreads();               // all waves done reading chunk kc
        if (kc < 7) {
            const unsigned short* src = wpk + (kc + 1) * 8192;
#pragma unroll
            for (int it = 0; it < 4; ++it) {
                int seg = it * 256 + tid;
                async_copy16u(src + seg * 8, sW + seg * 8);
            }
        }
#pragma unroll
        for (int mt = 0; mt < 2; ++mt) { aH[mt] = nH[mt]; aL[mt] = nL[mt]; }
    }

    // ---- epilogue: bias (+deg*dvec) (+ReLU), bf16 store, fused BN stats ----
    float B_[8], D_[8];
#pragma unroll
    for (int nt = 0; nt < 8; ++nt) {
        B_[nt] = bias[nt * 16 + ln];
        D_[nt] = NORM ? dvec[nt * 16 + ln] : 0.f;
    }
    float s8[8], q8[8];
#pragma unroll
    for (int nt = 0; nt < 8; ++nt) { s8[nt] = 0.f; q8[nt] = 0.f; }

#pragma unroll
    for (int mt = 0; mt < 2; ++mt) {
#pragma unroll
        for (int r = 0; r < 4; ++r) {
            int row = rowbase + mt * 16 + lg * 4 + r;
            if (row < M) {
                float dg = NORM ? degf[row] : 0.f;
#pragma unroll
                for (int nt = 0; nt < 8; ++nt) {
                    float v = acc[mt][nt][r] + B_[nt];
                    if (NORM) v += dg * D_[nt];
                    if (RELU) v = fmaxf(v, 0.f);
                    C[(size_t)row * NF + nt * 16 + ln] = (unsigned short)f2bf(v);
                    s8[nt] += v;
                    q8[nt] += v * v;
                }
            }
        }
    }

    __syncthreads();                   // done with sW as W buffer
    float* ssum = (float*)sW;          // [16][128]
    float* ssq  = ssum + 2048;
    const int rg = wid * 4 + lg;
#pragma unroll
    for (int nt = 0; nt < 8; ++nt) {
        ssum[rg * NF + nt * 16 + ln] = s8[nt];
        ssq [rg * NF + nt * 16 + ln] = q8[nt];
    }
    __syncthreads();
    if (tid < NF) {
        float s = 0.f, q = 0.f;
#pragma unroll
        for (int g = 0; g < 16; ++g) { s += ssum[g * NF + tid]; q += ssq[g * NF + tid]; }
        atomAddF(&gsum[tid], s);
        atomAddF(&gsq[tid], q);
    }
}

// ---------------------------------------------------------------------------
// Pooling (bf16 input): batch is SORTED -> run-length accumulate.
// ---------------------------------------------------------------------------
__global__ __launch_bounds__(TPB) void pool_kernel(
    const unsigned short* __restrict__ h, const int* __restrict__ batch,
    float* __restrict__ pooled, float* __restrict__ counts, int M)
{
    int base = blockIdx.x * 128;
    int col  = threadIdx.x & 127;
    int half = threadIdx.x >> 7;
    int end  = min(base + 128, M);
    float acc = 0.f; int cnt = 0; int gcur = -1;
    for (int n = base + half; n < end; n += 2) {
        int g = batch[n];
        if (g != gcur) {
            if (gcur >= 0) {
                atomAddF(&pooled[(size_t)gcur * NF + col], acc);
                if (col == 0) atomAddF(&counts[gcur], (float)cnt);
            }
            acc = 0.f; cnt = 0; gcur = g;
        }
        acc += bf2f((short)h[(size_t)n * NF + col]);
        cnt += 1;
    }
    if (gcur >= 0) {
        atomAddF(&pooled[(size_t)gcur * NF + col], acc);
        if (col == 0) atomAddF(&counts[gcur], (float)cnt);
    }
}

// Final: BN3 (computed inline) on pooled means, then @ Wlin + blin
__global__ __launch_bounds__(TPB) void final_kernel(
    const float* __restrict__ pooled, const float* __restrict__ counts,
    const float* __restrict__ gsum3, const float* __restrict__ gsq3,
    const float* __restrict__ g3, const float* __restrict__ be3,
    const float* __restrict__ Wlin, const float* __restrict__ blin,
    float* __restrict__ out, int G, int M)
{
    __shared__ float sa[128], sc[128];
    int t = threadIdx.x;
    if (t < 128) {
        float a, c;
        bn_ac(gsum3[t], gsq3[t], g3[t], be3[t], 1.0f / (float)M, &a, &c);
        sa[t] = a; sc[t] = c;
    }
    __syncthreads();
    int g = t;
    if (g >= G) return;
    float cntRaw = counts[g];
    float inv = 1.0f / fmaxf(cntRaw, 1.0f);
    float nonEmpty = cntRaw > 0.5f ? 1.0f : 0.0f;
    float acc0 = 0.f, acc1 = 0.f;
    for (int k = 0; k < NF; ++k) {
        float v = (sa[k] * pooled[(size_t)g * NF + k] * inv + sc[k]) * nonEmpty;
        acc0 += v * Wlin[k * 2 + 0];
        acc1 += v * Wlin[k * 2 + 1];
    }
    out[g * 2 + 0] = acc0 + blin[0];
    out[g * 2 + 1] = acc1 + blin[1];
}

// ---------------------------------------------------------------------------
extern "C" void kernel_launch(void* const* d_in, const int* in_sizes, int n_in,
                              void* d_out, int out_size, void* d_ws, size_t ws_size,
                              hipStream_t stream)
{
    const float* x     = (const float*)d_in[0];
    const int*   eidx  = (const int*)d_in[1];
    const int*   batch = (const int*)d_in[2];
    const float* W1r = (const float*)d_in[3],  *b1 = (const float*)d_in[4];
    const float* W1o = (const float*)d_in[5],  *g1 = (const float*)d_in[6],  *be1 = (const float*)d_in[7];
    const float* W2r = (const float*)d_in[8],  *b2 = (const float*)d_in[9];
    const float* W2o = (const float*)d_in[10], *g2 = (const float*)d_in[11], *be2 = (const float*)d_in[12];
    const float* W3r = (const float*)d_in[13], *b3 = (const float*)d_in[14];
    const float* W3o = (const float*)d_in[15], *g3 = (const float*)d_in[16], *be3 = (const float*)d_in[17];
    const float* Wlin = (const float*)d_in[18], *blin = (const float*)d_in[19];
    float* out = (float*)d_out;

    const int M = in_sizes[0] / NF;        // 100000 nodes (< 2^17 for pack)
    const int E = in_sizes[1] / 2;         // 1.6M edges
    const int G = out_size / 2;            // 256 graphs
    const int* src = eidx;
    const int* dst = eidx + E;
    const int nbuck = (M + 511) >> BSH;

    const size_t NODEF = (size_t)M * NF;

    // ---- workspace layout (four bf16 node-feature planes) ----
    unsigned short* agg_hi = (unsigned short*)d_ws;       // NODEF bf16
    unsigned short* agg_lo = agg_hi + NODEF;              // NODEF bf16
    unsigned short* xb     = agg_lo + NODEF;              // NODEF bf16
    unsigned short* hb     = xb + NODEF;                  // NODEF bf16
    float* zf   = (float*)(hb + NODEF);            // zeroed float zone
    float* gsum1 = zf;        float* gsq1 = zf + 128;
    float* gsum2 = zf + 256;  float* gsq2 = zf + 384;
    float* gsum3 = zf + 512;  float* gsq3 = zf + 640;
    float* counts = zf + 768;                      // G
    float* pooled = counts + G;                    // G*NF
    int*   zi   = (int*)(pooled + (size_t)G * NF); // zeroed int zone (1024)
    int* bucket_cnt = zi;                          // 256
    int* bucket_cur = zi + 256;                    // 256
    int* boff       = zi + 512;                    // nbuck+1 (<=257)
    int* ziEnd      = zi + 1024;
    float* ac = (float*)ziEnd;                     // fold outs
    float* bias2_2 = ac;        float* dvec2 = ac + 128;
    float* bias2_3 = ac + 256;  float* dvec3 = ac + 384;
    int* rowptr = (int*)(ac + 512);                // M+1
    int* srcs   = rowptr + (M + 1);                // E
    float* degf = (float*)(srcs + E);              // M
    uintptr_t pp = ((uintptr_t)(degf + M) + 15) & ~(uintptr_t)15;
    int* ppk = (int*)pp;                           // E packed edges (CSR build)
    // packed-W buffers UNION with ppk (dead before wsplit/fold run)
    unsigned short* wpk1 = (unsigned short*)pp;    // 65536 each (128 KB)
    unsigned short* wpk2 = wpk1 + 65536;
    unsigned short* wpk3 = wpk2 + 65536;

    const int gridEP       = (E + PE_EPB - 1) / PE_EPB;
    const int gatherBlocks = (int)(((size_t)M * 64 + TPB - 1) / TPB);
    const int gemmBlocks   = (M + 127) / 128;
    const int poolBlocks   = (M + 127) / 128;
    const int cvtBlocks    = (int)((NODEF / 8 + TPB - 1) / TPB);

    // single memset: float zone + int zone
    size_t zbytes = (char*)ziEnd - (char*)zf;
    hipMemsetAsync(zf, 0, zbytes, stream);

    // ---- bucketed reverse-CSR build (dst-grouped), reused by all 3 layers
    bucket_count   <<<gridEP, TPB, 0, stream>>>(dst, bucket_cnt, E, nbuck);
    bucket_scan    <<<1, TPB, 0, stream>>>(bucket_cnt, boff, bucket_cur, nbuck, E);
    partition_edges<<<gridEP, TPB, 0, stream>>>(src, dst, bucket_cur, ppk, E, nbuck);
    bucket_build   <<<nbuck, TPB, 0, stream>>>(ppk, boff, rowptr, srcs, degf, M, E);

    // ---- x -> bf16
    cvt_bf16<<<cvtBlocks, TPB, 0, stream>>>(x, xb, (int)(NODEF / 8));

    // ---- layer 1 (no incoming norm)
    wsplit_kernel<<<128, 256, 0, stream>>>(W1r, W1o, wpk1);
    gather_bf16<<<gatherBlocks, TPB, 0, stream>>>(xb, rowptr, srcs, agg_hi, agg_lo, M);
    gemm_mfma<true, false><<<gemmBlocks, TPB, 0, stream>>>(
        agg_hi, agg_lo, xb, wpk1, b1, nullptr, nullptr, hb, gsum1, gsq1, M);

    // ---- layer 2 (BN1 computed in fold, folded into weights)
    fold_kernel<<<128, 256, 0, stream>>>(gsum1, gsq1, g1, be1, W2r, W2o, b2,
                                         wpk2, bias2_2, dvec2, M);
    gather_bf16<<<gatherBlocks, TPB, 0, stream>>>(hb, rowptr, srcs, agg_hi, agg_lo, M);
    gemm_mfma<true, true><<<gemmBlocks, TPB, 0, stream>>>(
        agg_hi, agg_lo, hb, wpk2, bias2_2, dvec2, degf, hb, gsum2, gsq2, M);

    // ---- layer 3 (no ReLU; BN2 computed in fold, folded into weights)
    fold_kernel<<<128, 256, 0, stream>>>(gsum2, gsq2, g2, be2, W3r, W3o, b3,
                                         wpk3, bias2_3, dvec3, M);
    gather_bf16<<<gatherBlocks, TPB, 0, stream>>>(hb, rowptr, srcs, agg_hi, agg_lo, M);
    gemm_mfma<false, true><<<gemmBlocks, TPB, 0, stream>>>(
        agg_hi, agg_lo, hb, wpk3, bias2_3, dvec3, degf, hb, gsum3, gsq3, M);

    // ---- pool + classify (BN3 computed inline in final)
    pool_kernel<<<poolBlocks, TPB, 0, stream>>>(hb, batch, pooled, counts, M);
    final_kernel<<<1, TPB, 0, stream>>>(pooled, counts, gsum3, gsq3, g3, be3,
                                        Wlin, blin, out, G, M);
}

// Round 11
// 537.434 us; speedup vs baseline: 1.0645x; 1.0239x over previous
//
#include <hip/hip_runtime.h>
#include <math.h>
#include <stdint.h>

#define TPB 256
#define NF 128          // feature width (all layers)
#define BN_EPS_C 1e-5f
#define BSH 9           // bucket shift: 512 nodes per bucket
#define CAPSH 14        // fixed bucket capacity 16384 edges (mean 8192 + 90 sigma)
#define PE_EPB 4096     // edges per block in partition

typedef __attribute__((ext_vector_type(8))) short bf16x8;   // 8 bf16 (4 VGPRs)
typedef __attribute__((ext_vector_type(4))) float f32x4;    // 4 fp32
typedef __attribute__((ext_vector_type(2))) float f32x2;    // 2 fp32 (v_pk_add_f32)

// ---------------------------------------------------------------------------
__device__ __forceinline__ void atomAddF(float* p, float v) {
    unsafeAtomicAdd(p, v);
}

// fp32 <-> bf16 (RNE), bit-level
__device__ __forceinline__ short f2bf(float f) {
    unsigned u = __float_as_uint(f);
    unsigned r = (u + 0x7FFFu + ((u >> 16) & 1u)) >> 16;
    return (short)r;
}
__device__ __forceinline__ float bf2f(short b) {
    return __uint_as_float(((unsigned)(unsigned short)b) << 16);
}
__device__ __forceinline__ float bflo(unsigned u) { return __uint_as_float(u << 16); }
__device__ __forceinline__ float bfhi(unsigned u) { return __uint_as_float(u & 0xffff0000u); }
__device__ __forceinline__ unsigned packbf(float lo, float hi) {
    return (unsigned)(unsigned short)f2bf(lo) | ((unsigned)(unsigned short)f2bf(hi) << 16);
}

// async 16B global -> LDS DMA (global_load_lds dwordx4)
__device__ __forceinline__ void async_copy16u(const unsigned short* g, unsigned short* l) {
    __builtin_amdgcn_global_load_lds(
        (const __attribute__((address_space(1))) unsigned int*)g,
        (__attribute__((address_space(3))) unsigned int*)l, 16, 0, 0);
}

// BN fold: (a,c) from column sums
__device__ __forceinline__ void bn_ac(float gs, float gq, float gamma, float beta,
                                      float invM, float* a, float* c) {
    float mean = gs * invM;
    float var  = fmaxf(gq * invM - mean * mean, 0.f);
    float s    = gamma / sqrtf(var + BN_EPS_C);
    *a = s;
    *c = beta - mean * s;
}

// ===========================================================================
// Bucketed CSR build (dst-grouped), fixed-capacity regions: bucket b owns
// ppk/srcs range [b<<CAPSH, b<<CAPSH + cnt_b). No histogram/scan passes.
// ===========================================================================
__global__ __launch_bounds__(TPB) void init_cur(int* __restrict__ bucket_cur, int nbuck)
{
    int t = threadIdx.x;
    if (t < nbuck) bucket_cur[t] = t << CAPSH;
}

// Pack edge as src | (dst&511)<<17  (M < 2^17; bucket id implied by region)
__global__ __launch_bounds__(TPB) void partition_edges(
    const int* __restrict__ src, const int* __restrict__ dst,
    int* __restrict__ bucket_cur, int* __restrict__ ppk, int E, int nbuck)
{
    __shared__ int cnt[256];
    __shared__ int gbase[256];
    int t = threadIdx.x;
    cnt[t] = 0;
    __syncthreads();
    int base = blockIdx.x * PE_EPB;
    int myb[16], myrank[16], myp[16];
#pragma unroll
    for (int j = 0; j < 16; ++j) {
        int i = base + j * 256 + t;
        if (i < E) {
            int d = dst[i];
            int b = d >> BSH;
            myb[j] = b;
            myp[j] = src[i] | ((d & 511) << 17);
            myrank[j] = atomicAdd(&cnt[b], 1);
        } else myb[j] = -1;
    }
    __syncthreads();
    if (t < nbuck && cnt[t]) gbase[t] = atomicAdd(&bucket_cur[t], cnt[t]);
    __syncthreads();
#pragma unroll
    for (int j = 0; j < 16; ++j)
        if (myb[j] >= 0)
            ppk[gbase[myb[j]] + myrank[j]] = myp[j];
}

// One block per bucket: LDS degree count + scan -> rowptr/rowend/degf; local
// scatter of srcs into the bucket's contiguous (gapped) region.
__global__ __launch_bounds__(TPB) void bucket_build(
    const int* __restrict__ ppk, const int* __restrict__ bucket_cur,
    int* __restrict__ rowptr, int* __restrict__ rowend, int* __restrict__ srcs,
    float* __restrict__ degf, int M)
{
    __shared__ int ldeg[512];
    __shared__ int lsum[256];
    int b = blockIdx.x;
    int t = threadIdx.x;
    int n0 = b << BSH;
    int nn = min(512, M - n0);
    int p0 = b << CAPSH, p1 = bucket_cur[b];
    ldeg[t] = 0; ldeg[t + 256] = 0;
    __syncthreads();
    for (int i = p0 + t; i < p1; i += 256)
        atomicAdd(&ldeg[ppk[i] >> 17], 1);
    __syncthreads();
    int a0 = ldeg[2 * t], a1 = ldeg[2 * t + 1];
    lsum[t] = a0 + a1;
    __syncthreads();
    for (int off = 1; off < 256; off <<= 1) {
        int x = (t >= off) ? lsum[t - off] : 0;
        __syncthreads();
        lsum[t] += x;
        __syncthreads();
    }
    int excl = lsum[t] - (a0 + a1);
    int s0 = p0 + excl, s1 = p0 + excl + a0;
    ldeg[2 * t]     = s0;               // becomes scatter cursor
    ldeg[2 * t + 1] = s1;
    if (2 * t < nn) {
        rowptr[n0 + 2 * t] = s0; rowend[n0 + 2 * t] = s0 + a0;
        degf[n0 + 2 * t] = (float)a0;
    }
    if (2 * t + 1 < nn) {
        rowptr[n0 + 2 * t + 1] = s1; rowend[n0 + 2 * t + 1] = s1 + a1;
        degf[n0 + 2 * t + 1] = (float)a1;
    }
    __syncthreads();
    for (int i = p0 + t; i < p1; i += 256) {
        int v = ppk[i];
        int pos = atomicAdd(&ldeg[v >> 17], 1);
        srcs[pos] = v & 0x1FFFF;
    }
}

// ===========================================================================
// x -> bf16 convert (once)
// ===========================================================================
__global__ __launch_bounds__(TPB) void cvt_bf16(
    const float* __restrict__ x, unsigned short* __restrict__ xb, int n8)
{
    int i = blockIdx.x * TPB + threadIdx.x;
    if (i >= n8) return;
    const f32x4* p = (const f32x4*)(x + (size_t)i * 8);
    f32x4 v0 = p[0], v1 = p[1];
    uint4 o;
    o.x = packbf(v0.x, v0.y); o.y = packbf(v0.z, v0.w);
    o.z = packbf(v1.x, v1.y); o.w = packbf(v1.z, v1.w);
    *(uint4*)(xb + (size_t)i * 8) = o;
}

// ===========================================================================
// Gather aggregation (R10 winner, unchanged): one wave per node; 16-lane
// group g covers feats [li*8,+8) of edge e+grp; 8-edge flight; f32x2
// accumulators (v_pk_add_f32); low VGPR -> high occupancy. Output split
// into bf16 hi/lo planes for the GEMM.
// ===========================================================================
__device__ __forceinline__ void accp(f32x2* a, uint4 r) {
    a[0] += (f32x2){bflo(r.x), bfhi(r.x)};
    a[1] += (f32x2){bflo(r.y), bfhi(r.y)};
    a[2] += (f32x2){bflo(r.z), bfhi(r.z)};
    a[3] += (f32x2){bflo(r.w), bfhi(r.w)};
}

__global__ __launch_bounds__(TPB) void gather_bf16(
    const unsigned short* __restrict__ hb, const int* __restrict__ rowptr,
    const int* __restrict__ rowend, const int* __restrict__ srcs,
    unsigned short* __restrict__ agg_hi, unsigned short* __restrict__ agg_lo, int M)
{
    int wid = (blockIdx.x * TPB + threadIdx.x) >> 6;
    if (wid >= M) return;
    int lane = threadIdx.x & 63;
    int grp  = lane >> 4;
    int li   = lane & 15;
    int start = rowptr[wid], end = rowend[wid];
    const unsigned short* base = hb + li * 8;

    f32x2 A0[4], A1[4];
#pragma unroll
    for (int j = 0; j < 4; ++j) { A0[j] = (f32x2){0.f, 0.f}; A1[j] = A0[j]; }

    int e = start;
    for (; e + 7 < end; e += 8) {
        int s0 = srcs[e + grp];
        int s1 = srcs[e + 4 + grp];
        uint4 r0 = *(const uint4*)(base + (size_t)s0 * NF);
        uint4 r1 = *(const uint4*)(base + (size_t)s1 * NF);
        accp(A0, r0);
        accp(A1, r1);
    }
    if (e + 3 < end) {
        int s = srcs[e + grp];
        uint4 r = *(const uint4*)(base + (size_t)s * NF);
        accp(A0, r);
        e += 4;
    }
    int rem = end - e;                 // 0..3: predicated per-group tail
    if (grp < rem) {
        int s = srcs[e + grp];
        uint4 r = *(const uint4*)(base + (size_t)s * NF);
        accp(A1, r);
    }

#pragma unroll
    for (int j = 0; j < 4; ++j) A0[j] += A1[j];
    float v[8] = {A0[0].x, A0[0].y, A0[1].x, A0[1].y,
                  A0[2].x, A0[2].y, A0[3].x, A0[3].y};
#pragma unroll
    for (int j = 0; j < 8; ++j) v[j] += __shfl_xor(v[j], 16);
#pragma unroll
    for (int j = 0; j < 8; ++j) v[j] += __shfl_xor(v[j], 32);

    if (lane < 16) {
        float h[8], l[8];
#pragma unroll
        for (int j = 0; j < 8; ++j) {
            h[j] = bf2f(f2bf(v[j]));
            l[j] = v[j] - h[j];
        }
        uint4 oh, ol;
        oh.x = packbf(h[0], h[1]); oh.y = packbf(h[2], h[3]);
        oh.z = packbf(h[4], h[5]); oh.w = packbf(h[6], h[7]);
        ol.x = packbf(l[0], l[1]); ol.y = packbf(l[2], l[3]);
        ol.z = packbf(l[4], l[5]); ol.w = packbf(l[6], l[7]);
        *(uint4*)(agg_hi + (size_t)wid * NF + li * 8) = oh;
        *(uint4*)(agg_lo + (size_t)wid * NF + li * 8) = ol;
    }
}

// ===========================================================================
// W pack layout (per layer): 8 chunks of 16 KB, DMA-linear, bank-swizzled.
// ===========================================================================
__device__ __forceinline__ void wpack_store(
    unsigned short* __restrict__ wpk, int n, int k, float w)
{
    short h = f2bf(w);
    short l = f2bf(w - bf2f(h));
    int kc = k >> 5, grp = (k >> 3) & 3, el = k & 7;
    int base = kc * 8192 + n * 64;
    wpk[base + ((grp      ) ^ (n & 7)) * 8 + el] = (unsigned short)h;
    wpk[base + ((grp ^ 4) ^ (n & 7)) * 8 + el] = (unsigned short)l;
}

// Layer-1 W prep (no norm): transpose + concat + split + pack.
__global__ __launch_bounds__(256) void wsplit_kernel(
    const float* __restrict__ Wr, const float* __restrict__ Wo,
    unsigned short* __restrict__ wpk)
{
    int n = blockIdx.x;      // 0..127
    int k = threadIdx.x;     // 0..255
    float v = (k < NF) ? Wr[k * NF + n] : Wo[(k - NF) * NF + n];
    wpack_store(wpk, n, k, v);
}

// Fold previous-layer BN (computed inline from gsum/gsq) into this layer's
// weights; also bias2 = b + c@Wroot, dvec = c@Wr.
__global__ __launch_bounds__(256) void fold_kernel(
    const float* __restrict__ gsum, const float* __restrict__ gsq,
    const float* __restrict__ gamma, const float* __restrict__ beta,
    const float* __restrict__ Wr, const float* __restrict__ Wo,
    const float* __restrict__ b,
    unsigned short* __restrict__ wpk,
    float* __restrict__ bias2, float* __restrict__ dvec, int M)
{
    __shared__ float red[256];
    int n = blockIdx.x;
    int k = threadIdx.x;
    int kk = k & 127;
    float a, c;
    bn_ac(gsum[kk], gsq[kk], gamma[kk], beta[kk], 1.0f / (float)M, &a, &c);
    float w = (k < NF) ? Wr[k * NF + n] : Wo[kk * NF + n];
    float contrib = c * w;
    w *= a;
    wpack_store(wpk, n, k, w);
    red[k] = contrib;
    __syncthreads();
    for (int off = 64; off >= 1; off >>= 1) {
        if ((k & 127) < off) red[k] += red[k + off];
        __syncthreads();
    }
    if (k == 0)   dvec[n]  = red[0];
    if (k == 128) bias2[n] = b[n] + red[128];
}

// ===========================================================================
// MFMA dual GEMM v6 — W LDS-staged, A direct + reg prefetch.
// POOL variant (layer 3): h3 is consumed ONLY by mean-pool, so skip the C
// store entirely and accumulate into pooled[] via per-thread run-length
// (batch sorted -> <=2 graph runs per thread typical) + per-run atomics.
// ===========================================================================
template<bool RELU, bool NORM, bool POOL>
__global__ __launch_bounds__(TPB) void gemm_mfma(
    const unsigned short* __restrict__ Ahi, const unsigned short* __restrict__ Alo,
    const unsigned short* Ax,                                  // may alias C
    const unsigned short* __restrict__ wpk,
    const float* __restrict__ bias, const float* __restrict__ dvec,
    const float* __restrict__ degf, unsigned short* C,
    const int* __restrict__ batch, float* __restrict__ pooled,
    float* __restrict__ counts,
    float* __restrict__ gsum, float* __restrict__ gsq, int M)
{
    __shared__ unsigned short sW[8192];    // 16 KB W chunk; reused for stats

    const int tid  = threadIdx.x;
    const int wid  = tid >> 6;
    const int lane = tid & 63;
    const int lg   = lane >> 4;        // quad 0..3
    const int ln   = lane & 15;
    const int rowbase = blockIdx.x * 128 + wid * 32;

    f32x4 acc[2][8];
#pragma unroll
    for (int i = 0; i < 2; ++i)
#pragma unroll
        for (int j = 0; j < 8; ++j) acc[i][j] = (f32x4){0.f, 0.f, 0.f, 0.f};

    size_t aoff[2];
#pragma unroll
    for (int mt = 0; mt < 2; ++mt)
        aoff[mt] = (size_t)min(rowbase + mt * 16 + ln, M - 1) * NF + lg * 8;

    // DMA chunk 0 + preload agg kc=0 A frags
    {
#pragma unroll
        for (int it = 0; it < 4; ++it) {
            int seg = it * 256 + tid;
            async_copy16u(wpk + seg * 8, sW + seg * 8);
        }
    }
    bf16x8 aH[2], aL[2], nH[2], nL[2];
#pragma unroll
    for (int mt = 0; mt < 2; ++mt) {
        aH[mt] = *(const bf16x8*)(Ahi + aoff[mt]);
        aL[mt] = *(const bf16x8*)(Alo + aoff[mt]);
    }

#pragma unroll
    for (int kc = 0; kc < 8; ++kc) {
        __syncthreads();               // chunk kc resident in sW

        // ---- prefetch next chunk's A fragments into registers
        if (kc < 3) {
#pragma unroll
            for (int mt = 0; mt < 2; ++mt) {
                nH[mt] = *(const bf16x8*)(Ahi + aoff[mt] + (kc + 1) * 32);
                nL[mt] = *(const bf16x8*)(Alo + aoff[mt] + (kc + 1) * 32);
            }
        } else if (kc < 7) {           // next is root chunk (kc+1-4)*32
#pragma unroll
            for (int mt = 0; mt < 2; ++mt)
                nH[mt] = *(const bf16x8*)(Ax + aoff[mt] + (kc - 3) * 32);
        }

        // ---- compute on chunk kc (W from LDS)
#pragma unroll
        for (int nt = 0; nt < 8; ++nt) {
            int n = nt * 16 + ln;
            int boff = n * 64 + ((lg ^ (n & 7)) << 3);
            bf16x8 bhi = *(const bf16x8*)(sW + boff);
            bf16x8 blo = *(const bf16x8*)(sW + (boff ^ 32));
            if (kc < 4) {
#pragma unroll
                for (int mt = 0; mt < 2; ++mt) {
                    acc[mt][nt] = __builtin_amdgcn_mfma_f32_16x16x32_bf16(aH[mt], bhi, acc[mt][nt], 0, 0, 0);
                    acc[mt][nt] = __builtin_amdgcn_mfma_f32_16x16x32_bf16(aL[mt], bhi, acc[mt][nt], 0, 0, 0);
                    acc[mt][nt] = __builtin_amdgcn_mfma_f32_16x16x32_bf16(aH[mt], blo, acc[mt][nt], 0, 0, 0);
                }
            } else {
#pragma unroll
                for (int mt = 0; mt < 2; ++mt) {
                    acc[mt][nt] = __builtin_amdgcn_mfma_f32_16x16x32_bf16(aH[mt], bhi, acc[mt][nt], 0, 0, 0);
                    acc[mt][nt] = __builtin_amdgcn_mfma_f32_16x16x32_bf16(aH[mt], blo, acc[mt][nt], 0, 0, 0);
                }
            }
        }

        __syncthreads();               // all waves done reading chunk kc
        if (kc < 7) {
            const unsigned short* src = wpk + (kc + 1) * 8192;
#pragma unroll
            for (int it = 0; it < 4; ++it) {
                int seg = it * 256 + tid;
                async_copy16u(src + seg * 8, sW + seg * 8);
            }
        }
#pragma unroll
        for (int mt = 0; mt < 2; ++mt) { aH[mt] = nH[mt]; aL[mt] = nL[mt]; }
    }

    // ---- epilogue: bias (+deg*dvec) (+ReLU), store OR fused pool, BN stats
    float B_[8], D_[8];
#pragma unroll
    for (int nt = 0; nt < 8; ++nt) {
        B_[nt] = bias[nt * 16 + ln];
        D_[nt] = NORM ? dvec[nt * 16 + ln] : 0.f;
    }
    float s8[8], q8[8], pacc[8];
#pragma unroll
    for (int nt = 0; nt < 8; ++nt) { s8[nt] = 0.f; q8[nt] = 0.f; pacc[nt] = 0.f; }
    int gcur = -1, gcnt = 0;

#pragma unroll
    for (int mt = 0; mt < 2; ++mt) {
#pragma unroll
        for (int r = 0; r < 4; ++r) {
            int row = rowbase + mt * 16 + lg * 4 + r;   // strictly increasing
            if (row < M) {
                float dg = NORM ? degf[row] : 0.f;
                if (POOL) {
                    int g = batch[row];                  // wave-uniform per quad
                    if (g != gcur) {
                        if (gcur >= 0) {
#pragma unroll
                            for (int nt = 0; nt < 8; ++nt) {
                                atomAddF(&pooled[(size_t)gcur * NF + nt * 16 + ln], pacc[nt]);
                                pacc[nt] = 0.f;
                            }
                            if (ln == 0) atomAddF(&counts[gcur], (float)gcnt);
                        }
                        gcur = g; gcnt = 0;
                    }
                    gcnt++;
                }
#pragma unroll
                for (int nt = 0; nt < 8; ++nt) {
                    float v = acc[mt][nt][r] + B_[nt];
                    if (NORM) v += dg * D_[nt];
                    if (RELU) v = fmaxf(v, 0.f);
                    if (POOL) pacc[nt] += v;
                    else C[(size_t)row * NF + nt * 16 + ln] = (unsigned short)f2bf(v);
                    s8[nt] += v;
                    q8[nt] += v * v;
                }
            }
        }
    }
    if (POOL && gcur >= 0) {
#pragma unroll
        for (int nt = 0; nt < 8; ++nt)
            atomAddF(&pooled[(size_t)gcur * NF + nt * 16 + ln], pacc[nt]);
        if (ln == 0) atomAddF(&counts[gcur], (float)gcnt);
    }

    __syncthreads();                   // done with sW as W buffer
    float* ssum = (float*)sW;          // [16][128]
    float* ssq  = ssum + 2048;
    const int rg = wid * 4 + lg;
#pragma unroll
    for (int nt = 0; nt < 8; ++nt) {
        ssum[rg * NF + nt * 16 + ln] = s8[nt];
        ssq [rg * NF + nt * 16 + ln] = q8[nt];
    }
    __syncthreads();
    if (tid < NF) {
        float s = 0.f, q = 0.f;
#pragma unroll
        for (int g = 0; g < 16; ++g) { s += ssum[g * NF + tid]; q += ssq[g * NF + tid]; }
        atomAddF(&gsum[tid], s);
        atomAddF(&gsq[tid], q);
    }
}

// Final: BN3 (computed inline) on pooled means, then @ Wlin + blin
__global__ __launch_bounds__(TPB) void final_kernel(
    const float* __restrict__ pooled, const float* __restrict__ counts,
    const float* __restrict__ gsum3, const float* __restrict__ gsq3,
    const float* __restrict__ g3, const float* __restrict__ be3,
    const float* __restrict__ Wlin, const float* __restrict__ blin,
    float* __restrict__ out, int G, int M)
{
    __shared__ float sa[128], sc[128];
    int t = threadIdx.x;
    if (t < 128) {
        float a, c;
        bn_ac(gsum3[t], gsq3[t], g3[t], be3[t], 1.0f / (float)M, &a, &c);
        sa[t] = a; sc[t] = c;
    }
    __syncthreads();
    int g = t;
    if (g >= G) return;
    float cntRaw = counts[g];
    float inv = 1.0f / fmaxf(cntRaw, 1.0f);
    float nonEmpty = cntRaw > 0.5f ? 1.0f : 0.0f;
    float acc0 = 0.f, acc1 = 0.f;
    for (int k = 0; k < NF; ++k) {
        float v = (sa[k] * pooled[(size_t)g * NF + k] * inv + sc[k]) * nonEmpty;
        acc0 += v * Wlin[k * 2 + 0];
        acc1 += v * Wlin[k * 2 + 1];
    }
    out[g * 2 + 0] = acc0 + blin[0];
    out[g * 2 + 1] = acc1 + blin[1];
}

// ---------------------------------------------------------------------------
extern "C" void kernel_launch(void* const* d_in, const int* in_sizes, int n_in,
                              void* d_out, int out_size, void* d_ws, size_t ws_size,
                              hipStream_t stream)
{
    const float* x     = (const float*)d_in[0];
    const int*   eidx  = (const int*)d_in[1];
    const int*   batch = (const int*)d_in[2];
    const float* W1r = (const float*)d_in[3],  *b1 = (const float*)d_in[4];
    const float* W1o = (const float*)d_in[5],  *g1 = (const float*)d_in[6],  *be1 = (const float*)d_in[7];
    const float* W2r = (const float*)d_in[8],  *b2 = (const float*)d_in[9];
    const float* W2o = (const float*)d_in[10], *g2 = (const float*)d_in[11], *be2 = (const float*)d_in[12];
    const float* W3r = (const float*)d_in[13], *b3 = (const float*)d_in[14];
    const float* W3o = (const float*)d_in[15], *g3 = (const float*)d_in[16], *be3 = (const float*)d_in[17];
    const float* Wlin = (const float*)d_in[18], *blin = (const float*)d_in[19];
    float* out = (float*)d_out;

    const int M = in_sizes[0] / NF;        // 100000 nodes (< 2^17 for pack)
    const int E = in_sizes[1] / 2;         // 1.6M edges
    const int G = out_size / 2;            // 256 graphs
    const int* src = eidx;
    const int* dst = eidx + E;
    const int nbuck = (M + 511) >> BSH;

    const size_t NODEF = (size_t)M * NF;

    // ---- workspace layout (four bf16 node-feature planes) ----
    unsigned short* agg_hi = (unsigned short*)d_ws;       // NODEF bf16
    unsigned short* agg_lo = agg_hi + NODEF;              // NODEF bf16
    unsigned short* xb     = agg_lo + NODEF;              // NODEF bf16
    unsigned short* hb     = xb + NODEF;                  // NODEF bf16
    float* zf   = (float*)(hb + NODEF);            // zeroed float zone
    float* gsum1 = zf;        float* gsq1 = zf + 128;
    float* gsum2 = zf + 256;  float* gsq2 = zf + 384;
    float* gsum3 = zf + 512;  float* gsq3 = zf + 640;
    float* counts = zf + 768;                      // G
    float* pooled = counts + G;                    // G*NF
    int*   zi   = (int*)(pooled + (size_t)G * NF); // int zone (256)
    int* bucket_cur = zi;                          // 256 (init_cur overwrites)
    int* ziEnd      = zi + 256;
    float* ac = (float*)ziEnd;                     // fold outs
    float* bias2_2 = ac;        float* dvec2 = ac + 128;
    float* bias2_3 = ac + 256;  float* dvec3 = ac + 384;
    int* rowptr = (int*)(ac + 512);                // M
    int* rowend = rowptr + M;                      // M
    float* degf = (float*)(rowend + M);            // M
    int* srcs   = (int*)(degf + M);                // nbuck<<CAPSH (gapped)
    uintptr_t pp = ((uintptr_t)(srcs + ((size_t)nbuck << CAPSH)) + 15) & ~(uintptr_t)15;
    int* ppk = (int*)pp;                           // nbuck<<CAPSH packed edges
    // packed-W buffers UNION with ppk (dead before wsplit/fold run)
    unsigned short* wpk1 = (unsigned short*)pp;    // 65536 each (128 KB)
    unsigned short* wpk2 = wpk1 + 65536;
    unsigned short* wpk3 = wpk2 + 65536;

    const int gridEP       = (E + PE_EPB - 1) / PE_EPB;
    const int gatherBlocks = (int)(((size_t)M * 64 + TPB - 1) / TPB);
    const int gemmBlocks   = (M + 127) / 128;
    const int cvtBlocks    = (int)((NODEF / 8 + TPB - 1) / TPB);

    // single memset: float zone only (bucket_cur set by init_cur)
    size_t zbytes = (char*)ziEnd - (char*)zf;
    hipMemsetAsync(zf, 0, zbytes, stream);

    // ---- bucketed reverse-CSR build (fixed-cap regions; no hist/scan) ----
    init_cur       <<<1, TPB, 0, stream>>>(bucket_cur, nbuck);
    partition_edges<<<gridEP, TPB, 0, stream>>>(src, dst, bucket_cur, ppk, E, nbuck);
    bucket_build   <<<nbuck, TPB, 0, stream>>>(ppk, bucket_cur, rowptr, rowend, srcs, degf, M);

    // ---- x -> bf16
    cvt_bf16<<<cvtBlocks, TPB, 0, stream>>>(x, xb, (int)(NODEF / 8));

    // ---- layer 1 (no incoming norm)
    wsplit_kernel<<<128, 256, 0, stream>>>(W1r, W1o, wpk1);
    gather_bf16<<<gatherBlocks, TPB, 0, stream>>>(xb, rowptr, rowend, srcs, agg_hi, agg_lo, M);
    gemm_mfma<true, false, false><<<gemmBlocks, TPB, 0, stream>>>(
        agg_hi, agg_lo, xb, wpk1, b1, nullptr, nullptr, hb,
        nullptr, nullptr, nullptr, gsum1, gsq1, M);

    // ---- layer 2 (BN1 computed in fold, folded into weights)
    fold_kernel<<<128, 256, 0, stream>>>(gsum1, gsq1, g1, be1, W2r, W2o, b2,
                                         wpk2, bias2_2, dvec2, M);
    gather_bf16<<<gatherBlocks, TPB, 0, stream>>>(hb, rowptr, rowend, srcs, agg_hi, agg_lo, M);
    gemm_mfma<true, true, false><<<gemmBlocks, TPB, 0, stream>>>(
        agg_hi, agg_lo, hb, wpk2, bias2_2, dvec2, degf, hb,
        nullptr, nullptr, nullptr, gsum2, gsq2, M);

    // ---- layer 3 (no ReLU; BN2 folded; POOL fused: no h3 write, no pool pass)
    fold_kernel<<<128, 256, 0, stream>>>(gsum2, gsq2, g2, be2, W3r, W3o, b3,
                                         wpk3, bias2_3, dvec3, M);
    gather_bf16<<<gatherBlocks, TPB, 0, stream>>>(hb, rowptr, rowend, srcs, agg_hi, agg_lo, M);
    gemm_mfma<false, true, true><<<gemmBlocks, TPB, 0, stream>>>(
        agg_hi, agg_lo, hb, wpk3, bias2_3, dvec3, degf, hb,
        batch, pooled, counts, gsum3, gsq3, M);

    // ---- classify (BN3 computed inline in final)
    final_kernel<<<1, TPB, 0, stream>>>(pooled, counts, gsum3, gsq3, g3, be3,
                                        Wlin, blin, out, G, M);
}